// Round 12
// baseline (240.923 us; speedup 1.0000x reference)
//
#include <hip/hip_runtime.h>

#define NN 50000
#define NE 500000
#define HID 128
#define MT4 3128     // (782 mtiles) * 4 groups
#define MT4_PER_XCD 391
#define HISTB 1954   // ceil(NE/256)
#define SCAN_B 196   // ceil(NN/256)
#define CSRB 256     // csr_build grid (1 block/CU -> co-resident)

typedef __attribute__((ext_vector_type(8))) short short8;        // 16B container
typedef __attribute__((ext_vector_type(8))) _Float16 half8;      // 8 f16 = 16B
typedef __attribute__((ext_vector_type(2))) _Float16 half2v;
typedef __attribute__((ext_vector_type(4))) float f32x4;
typedef unsigned short ushort_t;
typedef unsigned int uint32;
typedef _Float16 half_t;

__device__ __forceinline__ ushort_t f2h(float f) {
    union { half_t h; ushort_t u; } x; x.h = (half_t)f; return x.u;   // v_cvt_f16_f32 RNE
}
__device__ __forceinline__ half2v u2h2(uint32 u) {
    union { uint32 u; half2v h; } x; x.u = u; return x.h;
}

// ---------------------------------------------------------------------------
// prep: pack both layers' weights (blocks 0..511), zero counts (512..707),
// zero barrier counters (block 708). One launch replaces pack + memset.
// ---------------------------------------------------------------------------
__global__ __launch_bounds__(256) void prep(
    const float* __restrict__ Wq1, const float* __restrict__ Wk1,
    const float* __restrict__ Wv1, const float* __restrict__ Ws1,
    const float* __restrict__ Wq2, const float* __restrict__ Wk2,
    const float* __restrict__ Wv2, const float* __restrict__ Ws2,
    ushort_t* __restrict__ Bt1, ushort_t* __restrict__ Bt2,
    int* __restrict__ counts, int* __restrict__ bars)
{
    int b = blockIdx.x, t = threadIdx.x;
    if (b < 512) {
        int idx = b * 256 + t;                       // [0, 131072)
        int layer = idx >> 16;
        int r = idx & 65535;
        int col = r >> 7;
        int kk = r & 127;
        int wsel = col >> 7;
        const float* W = (layer == 0)
            ? ((wsel == 0) ? Wq1 : (wsel == 1) ? Wk1 : (wsel == 2) ? Wv1 : Ws1)
            : ((wsel == 0) ? Wq2 : (wsel == 1) ? Wk2 : (wsel == 2) ? Wv2 : Ws2);
        float val = W[kk * HID + (col & 127)];
        if (wsel == 0) val *= 0.25f;                 // fold 1/sqrt(HEAD_DIM) into Wq
        (layer == 0 ? Bt1 : Bt2)[r] = f2h(val);
    } else if (b < 512 + SCAN_B) {
        int i = (b - 512) * 256 + t;
        if (i < NN) counts[i] = 0;
    } else {
        if (t < 8) bars[t] = 0;
    }
}

// ---------------------------------------------------------------------------
// MFMA GEMM body (f16), 64x128 tile per block = (mtile, weight g).
// XCD-bijective swizzle: the 4 g-blocks of one mtile land on one XCD.
// ---------------------------------------------------------------------------
template <int LAYER>
__device__ __forceinline__ void gemm_body(
    ushort_t* As, ushort_t* Bs, int wgid,
    const float* __restrict__ Xf, const ushort_t* __restrict__ Xh,
    const ushort_t* __restrict__ Bt,
    const float* __restrict__ bqp, const float* __restrict__ bkp,
    const float* __restrict__ bvp, const float* __restrict__ bsp,
    ushort_t* __restrict__ Qb, ushort_t* __restrict__ KVb, ushort_t* __restrict__ Sfb)
{
    const int xcd = wgid & 7, kidx = wgid >> 3;
    const int local = xcd * MT4_PER_XCD + kidx;
    const int mtile = local >> 2;
    const int g = local & 3;                         // 0=q 1=k 2=v 3=skip
    const int Mbase = mtile * 64;
    const int tid = threadIdx.x;
    const int lane = tid & 63, wave = tid >> 6;

    #pragma unroll
    for (int it = 0; it < 4; ++it) {                 // A: 1024 x 16B segs
        int lin = it * 256 + tid;
        int row = lin >> 4, s = lin & 15;
        int rg = Mbase + row; if (rg >= NN) rg = NN - 1;
        short8 v;
        if (LAYER == 1) {
            float4 f0 = *reinterpret_cast<const float4*>(Xf + (size_t)rg * HID + s * 8);
            float4 f1 = *reinterpret_cast<const float4*>(Xf + (size_t)rg * HID + s * 8 + 4);
            v[0] = (short)f2h(f0.x); v[1] = (short)f2h(f0.y);
            v[2] = (short)f2h(f0.z); v[3] = (short)f2h(f0.w);
            v[4] = (short)f2h(f1.x); v[5] = (short)f2h(f1.y);
            v[6] = (short)f2h(f1.z); v[7] = (short)f2h(f1.w);
        } else {
            v = *reinterpret_cast<const short8*>(Xh + (size_t)rg * HID + s * 8);
        }
        *reinterpret_cast<short8*>((char*)As + row * 256 + ((s * 16) ^ ((row & 7) * 16))) = v;
    }
    #pragma unroll
    for (int it = 0; it < 8; ++it) {                 // B: 128 cols x 128 k
        int lin = it * 256 + tid;
        int col = lin >> 4, s = lin & 15;
        short8 v = *reinterpret_cast<const short8*>(
            Bt + (size_t)(g * 128 + col) * HID + s * 8);
        *reinterpret_cast<short8*>((char*)Bs + col * 256 + ((s * 16) ^ ((col & 7) * 16))) = v;
    }
    __syncthreads();

    const int l15 = lane & 15;
    const int wrow = wave * 16;
    f32x4 acc[8] = {};
    #pragma unroll
    for (int kk = 0; kk < 4; ++kk) {
        int kbyte = kk * 64 + (lane >> 4) * 16;
        int ar = wrow + l15;
        half8 a = *reinterpret_cast<const half8*>(
            (const char*)As + ar * 256 + (kbyte ^ ((ar & 7) * 16)));
        #pragma unroll
        for (int nb = 0; nb < 8; ++nb) {
            int c = nb * 16 + l15;
            half8 b = *reinterpret_cast<const half8*>(
                (const char*)Bs + c * 256 + (kbyte ^ ((c & 7) * 16)));
            acc[nb] = __builtin_amdgcn_mfma_f32_16x16x32_f16(a, b, acc[nb], 0, 0, 0);
        }
    }
    __syncthreads();                                 // done reading As/Bs

    const float* bias = (g == 0) ? bqp : (g == 1) ? bkp : (g == 2) ? bvp : bsp;
    float* Cs = reinterpret_cast<float*>(Bs);        // 64x128 fp32 = 32KB
    #pragma unroll
    for (int nb = 0; nb < 8; ++nb) {
        int c = nb * 16 + l15;
        float bb = bias[c];
        if (g == 0) bb *= 0.25f;                     // match pre-scaled Wq
        #pragma unroll
        for (int r = 0; r < 4; ++r) {
            int rl = wrow + (lane >> 4) * 4 + r;     // C/D: col=lane&15, row=(lane>>4)*4+reg
            Cs[rl * 128 + c] = acc[nb][r] + bb;
        }
    }
    __syncthreads();

    #pragma unroll
    for (int it = 0; it < 4; ++it) {                 // 64 rows x 128 cols f16
        int lin = it * 256 + tid;
        int row = lin >> 4, s = lin & 15;            // 16 segs x 16B = 256B/row
        int rg = Mbase + row;
        if (rg < NN) {
            float4 v0 = *reinterpret_cast<float4*>(&Cs[row * 128 + s * 8]);
            float4 v1 = *reinterpret_cast<float4*>(&Cs[row * 128 + s * 8 + 4]);
            short8 o;
            o[0] = (short)f2h(v0.x); o[1] = (short)f2h(v0.y);
            o[2] = (short)f2h(v0.z); o[3] = (short)f2h(v0.w);
            o[4] = (short)f2h(v1.x); o[5] = (short)f2h(v1.y);
            o[6] = (short)f2h(v1.z); o[7] = (short)f2h(v1.w);
            ushort_t* dst = (g == 0) ? (Qb  + (size_t)rg * HID + s * 8)
                          : (g == 1) ? (KVb + (size_t)rg * 256 + s * 8)
                          : (g == 2) ? (KVb + (size_t)rg * 256 + 128 + s * 8)
                          :            (Sfb + (size_t)rg * HID + s * 8);
            *reinterpret_cast<short8*>(dst) = o;
        }
    }
}

// gemm layer 1 fused with the edge-histogram (independent work rides along).
__global__ __launch_bounds__(256) void gemm1_hist(
    const float* __restrict__ Xf, const ushort_t* __restrict__ Bt,
    const float* __restrict__ bqp, const float* __restrict__ bkp,
    const float* __restrict__ bvp, const float* __restrict__ bsp,
    ushort_t* __restrict__ Qb, ushort_t* __restrict__ KVb, ushort_t* __restrict__ Sfb,
    const int* __restrict__ dstIdx, int* __restrict__ counts)
{
    __shared__ ushort_t As[64 * 128];    // 16KB
    __shared__ ushort_t Bs[128 * 128];   // 32KB (reused as fp32 C-tile)
    if (blockIdx.x < MT4) {
        gemm_body<1>(As, Bs, blockIdx.x, Xf, nullptr, Bt,
                     bqp, bkp, bvp, bsp, Qb, KVb, Sfb);
    } else {
        int e = (blockIdx.x - MT4) * 256 + threadIdx.x;
        if (e < NE) atomicAdd(&counts[dstIdx[e]], 1);
    }
}

__global__ __launch_bounds__(256) void gemm2(
    const ushort_t* __restrict__ Xh, const ushort_t* __restrict__ Bt,
    const float* __restrict__ bqp, const float* __restrict__ bkp,
    const float* __restrict__ bvp, const float* __restrict__ bsp,
    ushort_t* __restrict__ Qb, ushort_t* __restrict__ KVb, ushort_t* __restrict__ Sfb)
{
    __shared__ ushort_t As[64 * 128];
    __shared__ ushort_t Bs[128 * 128];
    gemm_body<2>(As, Bs, blockIdx.x, nullptr, Xh, Bt,
                 bqp, bkp, bvp, bsp, Qb, KVb, Sfb);
}

// ---------------------------------------------------------------------------
// csr_build: block_sums -> scan -> write_offsets -> scatter in ONE kernel.
// 256 blocks (1/CU, co-resident by capacity). Software grid barriers:
// arrive = device-scope atomicAdd; spin = agent-scope atomic load (plain
// loads could read a stale non-coherent per-XCD L2 line forever).
// ---------------------------------------------------------------------------
__device__ __forceinline__ void grid_barrier(int* ctr)
{
    __syncthreads();
    if (threadIdx.x == 0) {
        __threadfence();
        atomicAdd(ctr, 1);
        while (__hip_atomic_load(ctr, __ATOMIC_RELAXED, __HIP_MEMORY_SCOPE_AGENT) < CSRB)
            __builtin_amdgcn_s_sleep(2);
        __threadfence();
    }
    __syncthreads();
}

__global__ __launch_bounds__(256) void csr_build(
    const int* __restrict__ src, const int* __restrict__ dst,
    const int* __restrict__ counts, int* __restrict__ bsum, int* __restrict__ bbase,
    int* __restrict__ offsets, int* __restrict__ cursor, int* __restrict__ csr_src,
    int* __restrict__ bars)
{
    __shared__ int sh[256];
    __shared__ int ws[4];
    const int t = threadIdx.x, b = blockIdx.x;

    // phase A: per-chunk sums
    if (b < SCAN_B) {
        int i = b * 256 + t;
        int v = (i < NN) ? counts[i] : 0;
        #pragma unroll
        for (int o = 1; o < 64; o <<= 1) v += __shfl_xor(v, o);
        if ((t & 63) == 0) ws[t >> 6] = v;
        __syncthreads();
        if (t == 0) bsum[b] = ws[0] + ws[1] + ws[2] + ws[3];
    }
    grid_barrier(bars + 0);

    // phase B: block 0 scans the 196 chunk sums
    if (b == 0) {
        int v = (t < SCAN_B) ? bsum[t] : 0;
        sh[t] = v;
        __syncthreads();
        for (int o = 1; o < 256; o <<= 1) {
            int u = (t >= o) ? sh[t - o] : 0;
            __syncthreads();
            sh[t] += u;
            __syncthreads();
        }
        if (t < SCAN_B) bbase[t] = (t > 0) ? sh[t - 1] : 0;
    }
    grid_barrier(bars + 1);

    // phase C: per-chunk exclusive offsets
    if (b < SCAN_B) {
        int i = b * 256 + t;
        int v = (i < NN) ? counts[i] : 0;
        sh[t] = v;
        __syncthreads();
        for (int o = 1; o < 256; o <<= 1) {
            int u = (t >= o) ? sh[t - o] : 0;
            __syncthreads();
            sh[t] += u;
            __syncthreads();
        }
        int excl = sh[t] - v + bbase[b];
        if (i < NN) { offsets[i] = excl; cursor[i] = excl; }
        if (i == NN - 1) offsets[NN] = excl + v;     // == NE
    }
    grid_barrier(bars + 2);

    // phase D: scatter (grid-stride)
    for (int e = b * 256 + t; e < NE; e += CSRB * 256) {
        int pos = atomicAdd(&cursor[dst[e]], 1);
        csr_src[pos] = src[e];
    }
}

// ---------------------------------------------------------------------------
// Edge aggregation (round-7 proven, at its gather roofline): one wave per
// node; 32 lanes per edge, 2 edges per wave instruction; lane owns 4 dims;
// f16 data; wave-uniform node/bounds (scalar loads). No max-sub softmax.
// ---------------------------------------------------------------------------
template <int LAYER>
__global__ __launch_bounds__(256) void edge_aggregate(
    const half_t* __restrict__ Qh, const half_t* __restrict__ KVh,
    const half_t* __restrict__ Sh,
    const int* __restrict__ offsets, const int* __restrict__ csr_src,
    const float* __restrict__ xres, const float* __restrict__ prelu_w,
    float* __restrict__ outF, ushort_t* __restrict__ outH)
{
    const int lane = threadIdx.x & 63;
    const int wid  = __builtin_amdgcn_readfirstlane((int)(threadIdx.x >> 6));
    const int node = blockIdx.x * 4 + wid;             // wave-uniform (SGPR)
    const bool hi  = lane >= 32;
    const int  c   = lane & 31;                        // dim-quad index

    uint2 qu = *reinterpret_cast<const uint2*>(Qh + (size_t)node * HID + c * 4);
    half2v qa = u2h2(qu.x), qb = u2h2(qu.y);
    const float q0 = (float)qa[0], q1 = (float)qa[1];  // scale pre-folded into Wq
    const float q2 = (float)qb[0], q3 = (float)qb[1];

    const int beg = offsets[node];                     // scalar loads
    const int end = offsets[node + 1];

    float den = 0.f, a0 = 0.f, a1 = 0.f, a2 = 0.f, a3 = 0.f;

#define COMPUTE(KU, VU) {                                                      \
        half2v k01 = u2h2((KU).x), k23 = u2h2((KU).y);                         \
        float p = (float)k01[0] * q0 + (float)k01[1] * q1                      \
                + (float)k23[0] * q2 + (float)k23[1] * q3;                     \
        p += __shfl_xor(p, 1); p += __shfl_xor(p, 2);                          \
        float w = __expf(p);                                                   \
        den += w;                                                              \
        half2v v01 = u2h2((VU).x), v23 = u2h2((VU).y);                         \
        a0 += w * (float)v01[0]; a1 += w * (float)v01[1];                      \
        a2 += w * (float)v23[0]; a3 += w * (float)v23[1]; }

    int i = beg;
    for (; i + 8 <= end; i += 8) {                     // 4 pairs = 8 edges
        uint2 ku[4], vu[4];
        #pragma unroll
        for (int j = 0; j < 4; ++j) {
            int s = hi ? csr_src[i + 2 * j + 1] : csr_src[i + 2 * j];
            const half_t* kv = KVh + (size_t)s * 256 + c * 4;
            ku[j] = *reinterpret_cast<const uint2*>(kv);
            vu[j] = *reinterpret_cast<const uint2*>(kv + 128);
        }
        #pragma unroll
        for (int j = 0; j < 4; ++j) COMPUTE(ku[j], vu[j])
    }
    for (; i + 2 <= end; i += 2) {                     // single pair
        int s = hi ? csr_src[i + 1] : csr_src[i];
        const half_t* kv = KVh + (size_t)s * 256 + c * 4;
        uint2 ku = *reinterpret_cast<const uint2*>(kv);
        uint2 vu = *reinterpret_cast<const uint2*>(kv + 128);
        COMPUTE(ku, vu)
    }
    if (i < end) {                                     // last single edge
        int s = csr_src[i];
        const half_t* kv = KVh + (size_t)s * 256 + c * 4;
        uint2 ku = *reinterpret_cast<const uint2*>(kv);
        uint2 vu = *reinterpret_cast<const uint2*>(kv + 128);
        half2v k01 = u2h2(ku.x), k23 = u2h2(ku.y);
        float p = (float)k01[0] * q0 + (float)k01[1] * q1
                + (float)k23[0] * q2 + (float)k23[1] * q3;
        p += __shfl_xor(p, 1); p += __shfl_xor(p, 2);
        float w = hi ? 0.f : __expf(p);
        den += w;
        half2v v01 = u2h2(vu.x), v23 = u2h2(vu.y);
        a0 += w * (float)v01[0]; a1 += w * (float)v01[1];
        a2 += w * (float)v23[0]; a3 += w * (float)v23[1];
    }
#undef COMPUTE

    // combine the two half-waves
    den += __shfl_xor(den, 32);
    a0 += __shfl_xor(a0, 32); a1 += __shfl_xor(a1, 32);
    a2 += __shfl_xor(a2, 32); a3 += __shfl_xor(a3, 32);

    if (!hi) {
        float inv = (den > 0.f) ? 1.f / den : 0.f;
        uint2 su = *reinterpret_cast<const uint2*>(Sh + (size_t)node * HID + c * 4);
        half2v s01 = u2h2(su.x), s23 = u2h2(su.y);
        float r0 = a0 * inv + (float)s01[0];
        float r1 = a1 * inv + (float)s01[1];
        float r2 = a2 * inv + (float)s23[0];
        float r3 = a3 * inv + (float)s23[1];
        if (LAYER == 2) {
            float4 xr = *reinterpret_cast<const float4*>(xres + (size_t)node * HID + c * 4);
            r0 += xr.x; r1 += xr.y; r2 += xr.z; r3 += xr.w;
        }
        const float al = prelu_w[0];
        r0 = fmaxf(r0, 0.f) + al * fminf(r0, 0.f);
        r1 = fmaxf(r1, 0.f) + al * fminf(r1, 0.f);
        r2 = fmaxf(r2, 0.f) + al * fminf(r2, 0.f);
        r3 = fmaxf(r3, 0.f) + al * fminf(r3, 0.f);
        if (LAYER == 1) {
            uint2 o;
            o.x = (uint32)f2h(r0) | ((uint32)f2h(r1) << 16);
            o.y = (uint32)f2h(r2) | ((uint32)f2h(r3) << 16);
            *reinterpret_cast<uint2*>(outH + (size_t)node * HID + c * 4) = o;
        } else {
            float4 o; o.x = r0; o.y = r1; o.z = r2; o.w = r3;
            *reinterpret_cast<float4*>(outF + (size_t)node * HID + c * 4) = o;
        }
    }
}

// ---------------------------------------------------------------------------
extern "C" void kernel_launch(void* const* d_in, const int* in_sizes, int n_in,
                              void* d_out, int out_size, void* d_ws, size_t ws_size,
                              hipStream_t stream)
{
    const float* x       = (const float*)d_in[0];
    const int*   ei      = (const int*)d_in[1];
    const float* prelu_w = (const float*)d_in[2];
    const float* Wq1 = (const float*)d_in[3],  *bq1 = (const float*)d_in[4];
    const float* Wk1 = (const float*)d_in[5],  *bk1 = (const float*)d_in[6];
    const float* Wv1 = (const float*)d_in[7],  *bv1 = (const float*)d_in[8];
    const float* Ws1 = (const float*)d_in[9],  *bs1 = (const float*)d_in[10];
    const float* Wq2 = (const float*)d_in[11], *bq2 = (const float*)d_in[12];
    const float* Wk2 = (const float*)d_in[13], *bk2 = (const float*)d_in[14];
    const float* Wv2 = (const float*)d_in[15], *bv2 = (const float*)d_in[16];
    const float* Ws2 = (const float*)d_in[17], *bs2 = (const float*)d_in[18];

    char* w = (char*)d_ws;
    size_t off = 0;
    auto alloc = [&](size_t bytes) { void* p = w + off; off += (bytes + 255) & ~(size_t)255; return p; };
    ushort_t* x1h  = (ushort_t*)alloc((size_t)NN * HID * 2);    // 12.8 MB (f16)
    ushort_t* Qb   = (ushort_t*)alloc((size_t)NN * HID * 2);    // 12.8 MB (f16)
    ushort_t* KVb  = (ushort_t*)alloc((size_t)NN * 256 * 2);    // 25.6 MB interleaved K|V
    ushort_t* Sfb  = (ushort_t*)alloc((size_t)NN * HID * 2);    // 12.8 MB (f16)
    ushort_t* Bt1  = (ushort_t*)alloc((size_t)512 * 128 * 2);
    ushort_t* Bt2  = (ushort_t*)alloc((size_t)512 * 128 * 2);
    int* counts  = (int*)alloc(NN * sizeof(int));
    int* bsum    = (int*)alloc(256 * sizeof(int));
    int* bbase   = (int*)alloc(256 * sizeof(int));
    int* offsets = (int*)alloc((NN + 1) * sizeof(int));
    int* cursor  = (int*)alloc(NN * sizeof(int));
    int* csr_src = (int*)alloc(NE * sizeof(int));
    int* bars    = (int*)alloc(8 * sizeof(int));
    (void)ws_size; (void)in_sizes; (void)n_in; (void)out_size;

    const int* srcIdx = ei;
    const int* dstIdx = ei + NE;

    // L1: pack weights + zero counts + zero barrier counters
    prep<<<512 + SCAN_B + 1, 256, 0, stream>>>(Wq1, Wk1, Wv1, Ws1,
                                               Wq2, Wk2, Wv2, Ws2,
                                               Bt1, Bt2, counts, bars);
    // L2: gemm layer 1 with the edge histogram fused in (independent work)
    gemm1_hist<<<MT4 + HISTB, 256, 0, stream>>>(x, Bt1, bq1, bk1, bv1, bs1,
                                                Qb, KVb, Sfb, dstIdx, counts);
    // L3: scan + scatter in one kernel (software grid barriers)
    csr_build<<<CSRB, 256, 0, stream>>>(srcIdx, dstIdx, counts, bsum, bbase,
                                        offsets, cursor, csr_src, bars);
    // L4: edge layer 1
    edge_aggregate<1><<<NN / 4, 256, 0, stream>>>((const half_t*)Qb, (const half_t*)KVb,
                                                  (const half_t*)Sfb, offsets, csr_src,
                                                  nullptr, prelu_w, nullptr, x1h);
    // L5: gemm layer 2
    gemm2<<<MT4, 256, 0, stream>>>(x1h, Bt2, bq2, bk2, bv2, bs2, Qb, KVb, Sfb);
    // L6: edge layer 2
    edge_aggregate<2><<<NN / 4, 256, 0, stream>>>((const half_t*)Qb, (const half_t*)KVb,
                                                  (const half_t*)Sfb, offsets, csr_src,
                                                  x, prelu_w, (float*)d_out, nullptr);
}

// Round 13
// 195.040 us; speedup vs baseline: 1.2353x; 1.2353x over previous
//
#include <hip/hip_runtime.h>

#define NN 50000
#define NE 500000
#define HID 128
#define MT4 3128     // (782 mtiles) * 4 groups
#define MT4_PER_XCD 391
#define HISTB 1954   // ceil(NE/256)
#define SCAN_B 196   // ceil(NN/256)

typedef __attribute__((ext_vector_type(8))) short short8;        // 16B container
typedef __attribute__((ext_vector_type(8))) _Float16 half8;      // 8 f16 = 16B
typedef __attribute__((ext_vector_type(2))) _Float16 half2v;
typedef __attribute__((ext_vector_type(4))) float f32x4;
typedef unsigned short ushort_t;
typedef unsigned int uint32;
typedef _Float16 half_t;

__device__ __forceinline__ ushort_t f2h(float f) {
    union { half_t h; ushort_t u; } x; x.h = (half_t)f; return x.u;   // v_cvt_f16_f32 RNE
}
__device__ __forceinline__ half2v u2h2(uint32 u) {
    union { uint32 u; half2v h; } x; x.u = u; return x.h;
}

// ---------------------------------------------------------------------------
// prep: pack both layers' weights (blocks 0..511), zero counts (512..707),
// zero the scan cursor (block 708).
// ---------------------------------------------------------------------------
__global__ __launch_bounds__(256) void prep(
    const float* __restrict__ Wq1, const float* __restrict__ Wk1,
    const float* __restrict__ Wv1, const float* __restrict__ Ws1,
    const float* __restrict__ Wq2, const float* __restrict__ Wk2,
    const float* __restrict__ Wv2, const float* __restrict__ Ws2,
    ushort_t* __restrict__ Bt1, ushort_t* __restrict__ Bt2,
    int* __restrict__ counts, int* __restrict__ gcursor)
{
    int b = blockIdx.x, t = threadIdx.x;
    if (b < 512) {
        int idx = b * 256 + t;                       // [0, 131072)
        int layer = idx >> 16;
        int r = idx & 65535;
        int col = r >> 7;
        int kk = r & 127;
        int wsel = col >> 7;
        const float* W = (layer == 0)
            ? ((wsel == 0) ? Wq1 : (wsel == 1) ? Wk1 : (wsel == 2) ? Wv1 : Ws1)
            : ((wsel == 0) ? Wq2 : (wsel == 1) ? Wk2 : (wsel == 2) ? Wv2 : Ws2);
        float val = W[kk * HID + (col & 127)];
        if (wsel == 0) val *= 0.25f;                 // fold 1/sqrt(HEAD_DIM) into Wq
        (layer == 0 ? Bt1 : Bt2)[r] = f2h(val);
    } else if (b < 512 + SCAN_B) {
        int i = (b - 512) * 256 + t;
        if (i < NN) counts[i] = 0;
    } else {
        if (t == 0) *gcursor = 0;
    }
}

// ---------------------------------------------------------------------------
// MFMA GEMM body (f16), 64x128 tile per block = (mtile, weight g).
// XCD-bijective swizzle: the 4 g-blocks of one mtile land on one XCD.
// ---------------------------------------------------------------------------
template <int LAYER>
__device__ __forceinline__ void gemm_body(
    ushort_t* As, ushort_t* Bs, int wgid,
    const float* __restrict__ Xf, const ushort_t* __restrict__ Xh,
    const ushort_t* __restrict__ Bt,
    const float* __restrict__ bqp, const float* __restrict__ bkp,
    const float* __restrict__ bvp, const float* __restrict__ bsp,
    ushort_t* __restrict__ Qb, ushort_t* __restrict__ KVb, ushort_t* __restrict__ Sfb)
{
    const int xcd = wgid & 7, kidx = wgid >> 3;
    const int local = xcd * MT4_PER_XCD + kidx;
    const int mtile = local >> 2;
    const int g = local & 3;                         // 0=q 1=k 2=v 3=skip
    const int Mbase = mtile * 64;
    const int tid = threadIdx.x;
    const int lane = tid & 63, wave = tid >> 6;

    #pragma unroll
    for (int it = 0; it < 4; ++it) {                 // A: 1024 x 16B segs
        int lin = it * 256 + tid;
        int row = lin >> 4, s = lin & 15;
        int rg = Mbase + row; if (rg >= NN) rg = NN - 1;
        short8 v;
        if (LAYER == 1) {
            float4 f0 = *reinterpret_cast<const float4*>(Xf + (size_t)rg * HID + s * 8);
            float4 f1 = *reinterpret_cast<const float4*>(Xf + (size_t)rg * HID + s * 8 + 4);
            v[0] = (short)f2h(f0.x); v[1] = (short)f2h(f0.y);
            v[2] = (short)f2h(f0.z); v[3] = (short)f2h(f0.w);
            v[4] = (short)f2h(f1.x); v[5] = (short)f2h(f1.y);
            v[6] = (short)f2h(f1.z); v[7] = (short)f2h(f1.w);
        } else {
            v = *reinterpret_cast<const short8*>(Xh + (size_t)rg * HID + s * 8);
        }
        *reinterpret_cast<short8*>((char*)As + row * 256 + ((s * 16) ^ ((row & 7) * 16))) = v;
    }
    #pragma unroll
    for (int it = 0; it < 8; ++it) {                 // B: 128 cols x 128 k
        int lin = it * 256 + tid;
        int col = lin >> 4, s = lin & 15;
        short8 v = *reinterpret_cast<const short8*>(
            Bt + (size_t)(g * 128 + col) * HID + s * 8);
        *reinterpret_cast<short8*>((char*)Bs + col * 256 + ((s * 16) ^ ((col & 7) * 16))) = v;
    }
    __syncthreads();

    const int l15 = lane & 15;
    const int wrow = wave * 16;
    f32x4 acc[8] = {};
    #pragma unroll
    for (int kk = 0; kk < 4; ++kk) {
        int kbyte = kk * 64 + (lane >> 4) * 16;
        int ar = wrow + l15;
        half8 a = *reinterpret_cast<const half8*>(
            (const char*)As + ar * 256 + (kbyte ^ ((ar & 7) * 16)));
        #pragma unroll
        for (int nb = 0; nb < 8; ++nb) {
            int c = nb * 16 + l15;
            half8 b = *reinterpret_cast<const half8*>(
                (const char*)Bs + c * 256 + (kbyte ^ ((c & 7) * 16)));
            acc[nb] = __builtin_amdgcn_mfma_f32_16x16x32_f16(a, b, acc[nb], 0, 0, 0);
        }
    }
    __syncthreads();                                 // done reading As/Bs

    const float* bias = (g == 0) ? bqp : (g == 1) ? bkp : (g == 2) ? bvp : bsp;
    float* Cs = reinterpret_cast<float*>(Bs);        // 64x128 fp32 = 32KB
    #pragma unroll
    for (int nb = 0; nb < 8; ++nb) {
        int c = nb * 16 + l15;
        float bb = bias[c];
        if (g == 0) bb *= 0.25f;                     // match pre-scaled Wq
        #pragma unroll
        for (int r = 0; r < 4; ++r) {
            int rl = wrow + (lane >> 4) * 4 + r;     // C/D: col=lane&15, row=(lane>>4)*4+reg
            Cs[rl * 128 + c] = acc[nb][r] + bb;
        }
    }
    __syncthreads();

    #pragma unroll
    for (int it = 0; it < 4; ++it) {                 // 64 rows x 128 cols f16
        int lin = it * 256 + tid;
        int row = lin >> 4, s = lin & 15;            // 16 segs x 16B = 256B/row
        int rg = Mbase + row;
        if (rg < NN) {
            float4 v0 = *reinterpret_cast<float4*>(&Cs[row * 128 + s * 8]);
            float4 v1 = *reinterpret_cast<float4*>(&Cs[row * 128 + s * 8 + 4]);
            short8 o;
            o[0] = (short)f2h(v0.x); o[1] = (short)f2h(v0.y);
            o[2] = (short)f2h(v0.z); o[3] = (short)f2h(v0.w);
            o[4] = (short)f2h(v1.x); o[5] = (short)f2h(v1.y);
            o[6] = (short)f2h(v1.z); o[7] = (short)f2h(v1.w);
            ushort_t* dst = (g == 0) ? (Qb  + (size_t)rg * HID + s * 8)
                          : (g == 1) ? (KVb + (size_t)rg * 256 + s * 8)
                          : (g == 2) ? (KVb + (size_t)rg * 256 + 128 + s * 8)
                          :            (Sfb + (size_t)rg * HID + s * 8);
            *reinterpret_cast<short8*>(dst) = o;
        }
    }
}

// gemm layer 1 fused with the edge-histogram (independent work rides along).
__global__ __launch_bounds__(256) void gemm1_hist(
    const float* __restrict__ Xf, const ushort_t* __restrict__ Bt,
    const float* __restrict__ bqp, const float* __restrict__ bkp,
    const float* __restrict__ bvp, const float* __restrict__ bsp,
    ushort_t* __restrict__ Qb, ushort_t* __restrict__ KVb, ushort_t* __restrict__ Sfb,
    const int* __restrict__ dstIdx, int* __restrict__ counts)
{
    __shared__ ushort_t As[64 * 128];    // 16KB
    __shared__ ushort_t Bs[128 * 128];   // 32KB (reused as fp32 C-tile)
    if (blockIdx.x < MT4) {
        gemm_body<1>(As, Bs, blockIdx.x, Xf, nullptr, Bt,
                     bqp, bkp, bvp, bsp, Qb, KVb, Sfb);
    } else {
        int e = (blockIdx.x - MT4) * 256 + threadIdx.x;
        if (e < NE) atomicAdd(&counts[dstIdx[e]], 1);
    }
}

__global__ __launch_bounds__(256) void gemm2(
    const ushort_t* __restrict__ Xh, const ushort_t* __restrict__ Bt,
    const float* __restrict__ bqp, const float* __restrict__ bkp,
    const float* __restrict__ bvp, const float* __restrict__ bsp,
    ushort_t* __restrict__ Qb, ushort_t* __restrict__ KVb, ushort_t* __restrict__ Sfb)
{
    __shared__ ushort_t As[64 * 128];
    __shared__ ushort_t Bs[128 * 128];
    gemm_body<2>(As, Bs, blockIdx.x, nullptr, Xh, Bt,
                 bqp, bkp, bvp, bsp, Qb, KVb, Sfb);
}

// ---------------------------------------------------------------------------
// Single-kernel scan: each block scans its 256-node chunk locally, then one
// atomicAdd claims a contiguous base. Chunk bases land in ARRIVAL order, not
// prefix order — valid because each node only needs a disjoint contiguous
// range; the edge kernel computes end = offsets[node] + counts[node].
// (Intra-node edge order is already atomic-nondeterministic since round 1.)
// ---------------------------------------------------------------------------
__global__ __launch_bounds__(256) void scan_fused(
    const int* __restrict__ counts, int* __restrict__ gcursor,
    int* __restrict__ offsets, int* __restrict__ cursor)
{
    __shared__ int sh[256];
    __shared__ int base_sh;
    const int t = threadIdx.x;
    const int i = blockIdx.x * 256 + t;
    int v = (i < NN) ? counts[i] : 0;
    sh[t] = v;
    __syncthreads();
    for (int o = 1; o < 256; o <<= 1) {
        int u = (t >= o) ? sh[t - o] : 0;
        __syncthreads();
        sh[t] += u;
        __syncthreads();
    }
    if (t == 255) base_sh = atomicAdd(gcursor, sh[255]);
    __syncthreads();
    int excl = sh[t] - v + base_sh;
    if (i < NN) { offsets[i] = excl; cursor[i] = excl; }
}

__global__ void scatter_kernel(const int* __restrict__ src, const int* __restrict__ dst,
                               int* __restrict__ cursor, int* __restrict__ csr_src)
{
    int e = blockIdx.x * blockDim.x + threadIdx.x;
    if (e < NE) {
        int pos = atomicAdd(&cursor[dst[e]], 1);
        csr_src[pos] = src[e];
    }
}

// ---------------------------------------------------------------------------
// Edge aggregation (round-7 proven, at its gather roofline): one wave per
// node; 32 lanes per edge, 2 edges per wave instruction; lane owns 4 dims;
// f16 data; wave-uniform node/bounds (scalar loads). No max-sub softmax.
// end = beg + counts[node] (offsets are arrival-ordered, not prefix-ordered).
// ---------------------------------------------------------------------------
template <int LAYER>
__global__ __launch_bounds__(256) void edge_aggregate(
    const half_t* __restrict__ Qh, const half_t* __restrict__ KVh,
    const half_t* __restrict__ Sh,
    const int* __restrict__ offsets, const int* __restrict__ counts,
    const int* __restrict__ csr_src,
    const float* __restrict__ xres, const float* __restrict__ prelu_w,
    float* __restrict__ outF, ushort_t* __restrict__ outH)
{
    const int lane = threadIdx.x & 63;
    const int wid  = __builtin_amdgcn_readfirstlane((int)(threadIdx.x >> 6));
    const int node = blockIdx.x * 4 + wid;             // wave-uniform (SGPR)
    const bool hi  = lane >= 32;
    const int  c   = lane & 31;                        // dim-quad index

    uint2 qu = *reinterpret_cast<const uint2*>(Qh + (size_t)node * HID + c * 4);
    half2v qa = u2h2(qu.x), qb = u2h2(qu.y);
    const float q0 = (float)qa[0], q1 = (float)qa[1];  // scale pre-folded into Wq
    const float q2 = (float)qb[0], q3 = (float)qb[1];

    const int beg = offsets[node];                     // scalar loads
    const int end = beg + counts[node];

    float den = 0.f, a0 = 0.f, a1 = 0.f, a2 = 0.f, a3 = 0.f;

#define COMPUTE(KU, VU) {                                                      \
        half2v k01 = u2h2((KU).x), k23 = u2h2((KU).y);                         \
        float p = (float)k01[0] * q0 + (float)k01[1] * q1                      \
                + (float)k23[0] * q2 + (float)k23[1] * q3;                     \
        p += __shfl_xor(p, 1); p += __shfl_xor(p, 2);                          \
        float w = __expf(p);                                                   \
        den += w;                                                              \
        half2v v01 = u2h2((VU).x), v23 = u2h2((VU).y);                         \
        a0 += w * (float)v01[0]; a1 += w * (float)v01[1];                      \
        a2 += w * (float)v23[0]; a3 += w * (float)v23[1]; }

    int i = beg;
    for (; i + 8 <= end; i += 8) {                     // 4 pairs = 8 edges
        uint2 ku[4], vu[4];
        #pragma unroll
        for (int j = 0; j < 4; ++j) {
            int s = hi ? csr_src[i + 2 * j + 1] : csr_src[i + 2 * j];
            const half_t* kv = KVh + (size_t)s * 256 + c * 4;
            ku[j] = *reinterpret_cast<const uint2*>(kv);
            vu[j] = *reinterpret_cast<const uint2*>(kv + 128);
        }
        #pragma unroll
        for (int j = 0; j < 4; ++j) COMPUTE(ku[j], vu[j])
    }
    for (; i + 2 <= end; i += 2) {                     // single pair
        int s = hi ? csr_src[i + 1] : csr_src[i];
        const half_t* kv = KVh + (size_t)s * 256 + c * 4;
        uint2 ku = *reinterpret_cast<const uint2*>(kv);
        uint2 vu = *reinterpret_cast<const uint2*>(kv + 128);
        COMPUTE(ku, vu)
    }
    if (i < end) {                                     // last single edge
        int s = csr_src[i];
        const half_t* kv = KVh + (size_t)s * 256 + c * 4;
        uint2 ku = *reinterpret_cast<const uint2*>(kv);
        uint2 vu = *reinterpret_cast<const uint2*>(kv + 128);
        half2v k01 = u2h2(ku.x), k23 = u2h2(ku.y);
        float p = (float)k01[0] * q0 + (float)k01[1] * q1
                + (float)k23[0] * q2 + (float)k23[1] * q3;
        p += __shfl_xor(p, 1); p += __shfl_xor(p, 2);
        float w = hi ? 0.f : __expf(p);
        den += w;
        half2v v01 = u2h2(vu.x), v23 = u2h2(vu.y);
        a0 += w * (float)v01[0]; a1 += w * (float)v01[1];
        a2 += w * (float)v23[0]; a3 += w * (float)v23[1];
    }
#undef COMPUTE

    // combine the two half-waves
    den += __shfl_xor(den, 32);
    a0 += __shfl_xor(a0, 32); a1 += __shfl_xor(a1, 32);
    a2 += __shfl_xor(a2, 32); a3 += __shfl_xor(a3, 32);

    if (!hi) {
        float inv = (den > 0.f) ? 1.f / den : 0.f;
        uint2 su = *reinterpret_cast<const uint2*>(Sh + (size_t)node * HID + c * 4);
        half2v s01 = u2h2(su.x), s23 = u2h2(su.y);
        float r0 = a0 * inv + (float)s01[0];
        float r1 = a1 * inv + (float)s01[1];
        float r2 = a2 * inv + (float)s23[0];
        float r3 = a3 * inv + (float)s23[1];
        if (LAYER == 2) {
            float4 xr = *reinterpret_cast<const float4*>(xres + (size_t)node * HID + c * 4);
            r0 += xr.x; r1 += xr.y; r2 += xr.z; r3 += xr.w;
        }
        const float al = prelu_w[0];
        r0 = fmaxf(r0, 0.f) + al * fminf(r0, 0.f);
        r1 = fmaxf(r1, 0.f) + al * fminf(r1, 0.f);
        r2 = fmaxf(r2, 0.f) + al * fminf(r2, 0.f);
        r3 = fmaxf(r3, 0.f) + al * fminf(r3, 0.f);
        if (LAYER == 1) {
            uint2 o;
            o.x = (uint32)f2h(r0) | ((uint32)f2h(r1) << 16);
            o.y = (uint32)f2h(r2) | ((uint32)f2h(r3) << 16);
            *reinterpret_cast<uint2*>(outH + (size_t)node * HID + c * 4) = o;
        } else {
            float4 o; o.x = r0; o.y = r1; o.z = r2; o.w = r3;
            *reinterpret_cast<float4*>(outF + (size_t)node * HID + c * 4) = o;
        }
    }
}

// ---------------------------------------------------------------------------
extern "C" void kernel_launch(void* const* d_in, const int* in_sizes, int n_in,
                              void* d_out, int out_size, void* d_ws, size_t ws_size,
                              hipStream_t stream)
{
    const float* x       = (const float*)d_in[0];
    const int*   ei      = (const int*)d_in[1];
    const float* prelu_w = (const float*)d_in[2];
    const float* Wq1 = (const float*)d_in[3],  *bq1 = (const float*)d_in[4];
    const float* Wk1 = (const float*)d_in[5],  *bk1 = (const float*)d_in[6];
    const float* Wv1 = (const float*)d_in[7],  *bv1 = (const float*)d_in[8];
    const float* Ws1 = (const float*)d_in[9],  *bs1 = (const float*)d_in[10];
    const float* Wq2 = (const float*)d_in[11], *bq2 = (const float*)d_in[12];
    const float* Wk2 = (const float*)d_in[13], *bk2 = (const float*)d_in[14];
    const float* Wv2 = (const float*)d_in[15], *bv2 = (const float*)d_in[16];
    const float* Ws2 = (const float*)d_in[17], *bs2 = (const float*)d_in[18];

    char* w = (char*)d_ws;
    size_t off = 0;
    auto alloc = [&](size_t bytes) { void* p = w + off; off += (bytes + 255) & ~(size_t)255; return p; };
    ushort_t* x1h  = (ushort_t*)alloc((size_t)NN * HID * 2);    // 12.8 MB (f16)
    ushort_t* Qb   = (ushort_t*)alloc((size_t)NN * HID * 2);    // 12.8 MB (f16)
    ushort_t* KVb  = (ushort_t*)alloc((size_t)NN * 256 * 2);    // 25.6 MB interleaved K|V
    ushort_t* Sfb  = (ushort_t*)alloc((size_t)NN * HID * 2);    // 12.8 MB (f16)
    ushort_t* Bt1  = (ushort_t*)alloc((size_t)512 * 128 * 2);
    ushort_t* Bt2  = (ushort_t*)alloc((size_t)512 * 128 * 2);
    int* counts  = (int*)alloc(NN * sizeof(int));
    int* offsets = (int*)alloc(NN * sizeof(int));
    int* cursor  = (int*)alloc(NN * sizeof(int));
    int* csr_src = (int*)alloc(NE * sizeof(int));
    int* gcursor = (int*)alloc(256);
    (void)ws_size; (void)in_sizes; (void)n_in; (void)out_size;

    const int* srcIdx = ei;
    const int* dstIdx = ei + NE;

    // L1: pack weights + zero counts + zero scan cursor
    prep<<<512 + SCAN_B + 1, 256, 0, stream>>>(Wq1, Wk1, Wv1, Ws1,
                                               Wq2, Wk2, Wv2, Ws2,
                                               Bt1, Bt2, counts, gcursor);
    // L2: gemm layer 1 with the edge histogram fused in (independent work)
    gemm1_hist<<<MT4 + HISTB, 256, 0, stream>>>(x, Bt1, bq1, bk1, bv1, bs1,
                                                Qb, KVb, Sfb, dstIdx, counts);
    // L3: one-kernel scan (atomic chunk bases, arrival order)
    scan_fused<<<SCAN_B, 256, 0, stream>>>(counts, gcursor, offsets, cursor);
    // L4: scatter (wide grid)
    scatter_kernel<<<(NE + 255) / 256, 256, 0, stream>>>(srcIdx, dstIdx, cursor, csr_src);
    // L5: edge layer 1
    edge_aggregate<1><<<NN / 4, 256, 0, stream>>>((const half_t*)Qb, (const half_t*)KVb,
                                                  (const half_t*)Sfb, offsets, counts, csr_src,
                                                  nullptr, prelu_w, nullptr, x1h);
    // L6: gemm layer 2
    gemm2<<<MT4, 256, 0, stream>>>(x1h, Bt2, bq2, bk2, bv2, bs2, Qb, KVb, Sfb);
    // L7: edge layer 2
    edge_aggregate<2><<<NN / 4, 256, 0, stream>>>((const half_t*)Qb, (const half_t*)KVb,
                                                  (const half_t*)Sfb, offsets, counts, csr_src,
                                                  x, prelu_w, (float*)d_out, nullptr);
}